// Round 6
// baseline (319.599 us; speedup 1.0000x reference)
//
#include <hip/hip_runtime.h>
#include <math.h>

#define NSEQ   3136      // N0 = 56*56
#define NTOK   25088     // B * NSEQ
#define BATCH  8
#define WID    56
#define NHEADS 8
#define HDIM   32
#define CDIM   256
#define PLEN   49
#define NEGC  -1000000000.0f

#define TJ     28        // pixels per block (half an image row)
#define NLOC   90        // 3 rows x 30 cols of local keys
#define KT     168       // A_all / V_T stride in halfs (160 keys + pad)

typedef __attribute__((ext_vector_type(8))) short short8;
typedef __attribute__((ext_vector_type(4))) float f32x4;
typedef __attribute__((ext_vector_type(8))) _Float16 half8;
typedef __attribute__((ext_vector_type(4))) _Float16 half4_t;
typedef __attribute__((ext_vector_type(2))) _Float16 half2_t;

__device__ __forceinline__ float gelu_exact(float x) {
    return 0.5f * x * (1.0f + erff(x * 0.70710678118654752440f));
}

__device__ __forceinline__ unsigned short f2bf(float f) {
    unsigned int u = __float_as_uint(f);
    u += 0x7fffu + ((u >> 16) & 1u);
    return (unsigned short)(u >> 16);
}

__device__ __forceinline__ void gl_lds16(const void* g, void* l) {
    __builtin_amdgcn_global_load_lds(
        (const __attribute__((address_space(1))) void*)g,
        (__attribute__((address_space(3))) void*)l, 16, 0, 0);
}

// ---------------------------------------------------------------------------
// bf16 MFMA GEMM (m97 structure), segmented epilogue with fused per-head
// L2-norm. AF32=1: A fp32 staged via gl_lds with XOR-swizzle, cvt to bf16 at
// fragment read. act segment (sr-gelu): output is NOT stored — it is
// 8x8-pooled on the fly via atomicAdd into xpa[b][p][c] (value pre-scaled
// by 1/64). This removes the 103MB xs write + 103MB pool_ln re-read.
// ---------------------------------------------------------------------------
template<int NORM, int AF32>
__global__ __launch_bounds__(256) void gemm_bt(
    const void* __restrict__ Araw,
    const unsigned short* __restrict__ Bt,
    const float* __restrict__ b0, const float* __restrict__ b1,
    const float* __restrict__ b2,
    float* __restrict__ o0, float* __restrict__ o1, float* __restrict__ o2,
    float* __restrict__ xpa)
{
    __shared__ char AsBuf[AF32 ? 16384 : 8192];
    __shared__ short Bs[4096];
    const int tid = threadIdx.x;
    const int w = tid >> 6, lane = tid & 63;

    // XCD-chunked swizzle: 8 consecutive chunks of the grid -> 8 XCDs.
    const int nwg = gridDim.x * gridDim.y;
    const int id  = blockIdx.y * gridDim.x + blockIdx.x;
    const int swz = (id & 7) * (nwg >> 3) + (id >> 3);
    const int bm = (swz / gridDim.x) * 128;
    const int bn = (swz % gridDim.x) * 128;

    const int m0 = (w >> 1) * 64, n0 = (w & 1) * 64;
    const int lr = lane & 15, q8 = (lane >> 4) * 8, quad = lane >> 4;

    f32x4 acc[4][4] = {};

    char* bB = (char*)Bs + w * 1024;
    const unsigned short* Bp0 = Bt + (size_t)(bn + (tid >> 2)) * 256 + (tid & 3) * 8;
    const unsigned short* Bp1 = Bt + (size_t)(bn + (tid >> 2) + 64) * 256 + (tid & 3) * 8;

    // A staging pointers
    const unsigned short* Ap0b; const unsigned short* Ap1b;
    const float *Af0, *Af1, *Af2, *Af3;
    char* aB;
    if constexpr (AF32) {
        const float* Af = (const float*)Araw;
        const int r8 = tid >> 3;                       // rel row 0..31
        const int xc = ((tid & 7) ^ (r8 & 7)) * 4;     // inverse-swizzled col
        Af0 = Af + (size_t)(bm + r8      ) * 256 + xc;
        Af1 = Af + (size_t)(bm + r8 + 32 ) * 256 + xc;
        Af2 = Af + (size_t)(bm + r8 + 64 ) * 256 + xc;
        Af3 = Af + (size_t)(bm + r8 + 96 ) * 256 + xc;
        aB = (char*)AsBuf + w * 1024;
    } else {
        const unsigned short* Ab = (const unsigned short*)Araw;
        Ap0b = Ab + (size_t)(bm + (tid >> 2)) * 256 + (tid & 3) * 8;
        Ap1b = Ab + (size_t)(bm + (tid >> 2) + 64) * 256 + (tid & 3) * 8;
        aB = (char*)AsBuf + w * 1024;
    }

    for (int k0 = 0; k0 < 256; k0 += 32) {
        if (k0) __syncthreads();
        if constexpr (AF32) {
            gl_lds16(Af0 + k0, aB);
            gl_lds16(Af1 + k0, aB + 4096);
            gl_lds16(Af2 + k0, aB + 8192);
            gl_lds16(Af3 + k0, aB + 12288);
        } else {
            gl_lds16(Ap0b + k0, aB);
            gl_lds16(Ap1b + k0, aB + 4096);
        }
        gl_lds16(Bp0 + k0, bB);
        gl_lds16(Bp1 + k0, bB + 4096);
        __syncthreads();
        short8 af[4], bf[4];
        if constexpr (AF32) {
            const char* Ab = (const char*)AsBuf;
            #pragma unroll
            for (int t = 0; t < 4; t++) {
                int R = m0 + t * 16 + lr;
                int c0b = R * 128 + ((((quad << 1) | 0) ^ (R & 7)) << 4);
                int c1b = R * 128 + ((((quad << 1) | 1) ^ (R & 7)) << 4);
                f32x4 x0 = *reinterpret_cast<const f32x4*>(Ab + c0b);
                f32x4 x1 = *reinterpret_cast<const f32x4*>(Ab + c1b);
                union { int i4[4]; short8 s8; } u;
                asm("v_cvt_pk_bf16_f32 %0, %1, %2" : "=v"(u.i4[0]) : "v"(x0[0]), "v"(x0[1]));
                asm("v_cvt_pk_bf16_f32 %0, %1, %2" : "=v"(u.i4[1]) : "v"(x0[2]), "v"(x0[3]));
                asm("v_cvt_pk_bf16_f32 %0, %1, %2" : "=v"(u.i4[2]) : "v"(x1[0]), "v"(x1[1]));
                asm("v_cvt_pk_bf16_f32 %0, %1, %2" : "=v"(u.i4[3]) : "v"(x1[2]), "v"(x1[3]));
                af[t] = u.s8;
            }
        } else {
            const short* As16 = (const short*)AsBuf;
            #pragma unroll
            for (int t = 0; t < 4; t++)
                af[t] = *reinterpret_cast<const short8*>(&As16[(m0 + t * 16 + lr) * 32 + q8]);
        }
        #pragma unroll
        for (int t = 0; t < 4; t++)
            bf[t] = *reinterpret_cast<const short8*>(&Bs[(n0 + t * 16 + lr) * 32 + q8]);
        #pragma unroll
        for (int mt = 0; mt < 4; mt++)
            #pragma unroll
            for (int nt = 0; nt < 4; nt++)
                acc[mt][nt] = __builtin_amdgcn_mfma_f32_16x16x32_bf16(
                    af[mt], bf[nt], acc[mt][nt], 0, 0, 0);
    }

    const float* bp; float* op; int ostr; int c0; bool act = false;
    if (bn < 256)      { bp = b0; op = o0; ostr = 256; c0 = bn; }
    else if (bn < 768) { bp = b1; op = o1; ostr = 512; c0 = bn - 256; }
    else               { bp = b2; op = o2; ostr = 256; c0 = bn - 768; act = true; }
    const bool donorm = NORM && (bn < 512);

    float bv[4];
    #pragma unroll
    for (int nt = 0; nt < 4; nt++) bv[nt] = bp[c0 + n0 + nt * 16 + lr];

    #pragma unroll
    for (int mt = 0; mt < 4; mt++) {
        #pragma unroll
        for (int r = 0; r < 4; r++) {
            float ov[4];
            #pragma unroll
            for (int nt = 0; nt < 4; nt++) ov[nt] = acc[mt][nt][r] + bv[nt];
            int m = bm + m0 + mt * 16 + quad * 4 + r;
            if (act) {
                // fused gelu + 8x8-pool accumulate (value pre-scaled by 1/64)
                #pragma unroll
                for (int nt = 0; nt < 4; nt++)
                    ov[nt] = gelu_exact(ov[nt]) * 0.015625f;
                int bb2 = m / NSEQ;
                int pix = m - bb2 * NSEQ;
                int ii = pix / WID, jj = pix - ii * WID;
                int p = (ii >> 3) * 7 + (jj >> 3);
                float* dst = xpa + ((size_t)(bb2 * PLEN + p)) * CDIM + c0 + n0;
                #pragma unroll
                for (int nt = 0; nt < 4; nt++)
                    atomicAdd(dst + nt * 16 + lr, ov[nt]);
            } else {
                if (donorm) {
                    float s01 = ov[0] * ov[0] + ov[1] * ov[1];
                    float s23 = ov[2] * ov[2] + ov[3] * ov[3];
                    #pragma unroll
                    for (int mm = 1; mm < 16; mm <<= 1) {
                        s01 += __shfl_xor(s01, mm);
                        s23 += __shfl_xor(s23, mm);
                    }
                    float r01 = 1.0f / fmaxf(sqrtf(s01), 1e-12f);
                    float r23 = 1.0f / fmaxf(sqrtf(s23), 1e-12f);
                    ov[0] *= r01; ov[1] *= r01; ov[2] *= r23; ov[3] *= r23;
                }
                #pragma unroll
                for (int nt = 0; nt < 4; nt++)
                    op[(size_t)m * ostr + c0 + n0 + nt * 16 + lr] = ov[nt];
            }
        }
    }
}

// ---------------------------------------------------------------------------
// Merged prep: [0,1024) wcat | [1024,1152) cpb | [1152,1162) tables |
// [1162,1274) lmask | [1274,1372) zero xpa
// ---------------------------------------------------------------------------
__global__ __launch_bounds__(256) void prep_misc(
    const float* __restrict__ qw, const float* __restrict__ kvw,
    const float* __restrict__ srw, unsigned short* __restrict__ wcat,
    const float* __restrict__ rct, const float* __restrict__ fc1w,
    const float* __restrict__ fc1b, const float* __restrict__ fc2w,
    const float* __restrict__ fc2b, float* __restrict__ tab,
    const float* __restrict__ temp, const float* __restrict__ sls,
    const float* __restrict__ qe,  const float* __restrict__ lt,
    const float* __restrict__ lb,
    float* __restrict__ scaleT, float* __restrict__ corrT,
    float* __restrict__ ltT, uint2* __restrict__ lmask,
    float* __restrict__ xpa)
{
    int bid = blockIdx.x, tid = threadIdx.x;
    if (bid < 1024) {
        int gid = bid * 256 + tid;
        int n = gid >> 8, k = gid & 255;
        float v;
        if (n < 256)      v = qw[k * 256 + n];
        else if (n < 768) v = kvw[k * 512 + (n - 256)];
        else              v = srw[k * 256 + (n - 768)];
        wcat[gid] = f2bf(v);
    } else if (bid < 1152) {
        int gid = (bid - 1024) * 256 + tid;
        if (gid >= 4096 * 8) return;
        int t = gid >> 3, h = gid & 7;
        float c0 = rct[t * 2 + 0], c1 = rct[t * 2 + 1];
        float acc = 0.f;
        for (int i = 0; i < 512; i++) {
            float hid = fmaxf(c0 * fc1w[i] + c1 * fc1w[512 + i] + fc1b[i], 0.f);
            acc += hid * fc2w[i * 8 + h];
        }
        tab[t * 8 + h] = acc + fc2b[h];
    } else if (bid < 1162) {
        int g = (bid - 1152) * 256 + tid;
        if (g < 8) {
            scaleT[g] = log1pf(expf(temp[g])) * sls[0];
        } else if (g < 80) {
            int h = (g - 8) / 9, e = (g - 8) % 9;
            float s = 0.f;
            for (int d = 0; d < 32; d++) s += qe[h * 32 + d] * lt[(h * 32 + d) * 9 + e];
            corrT[h * 9 + e] = lb[h * 9 + e] - s;
        } else if (g < 80 + 8 * 9 * 32) {
            int g2 = g - 80;
            int h = g2 / 288, rem = g2 % 288;
            int e = rem / 32, d = rem & 31;
            ltT[(h * 9 + e) * 32 + d] = lt[(h * 32 + d) * 9 + e];
        }
    } else if (bid < 1274) {
        int pos = bid - 1162;               // 0..111 = (i, half)
        int i = pos >> 1, half = pos & 1;
        int j0 = half * TJ;
        int w = tid >> 6, lane = tid & 63;
        int lr = lane & 15, quad = lane >> 4;
        int kh = w >> 1, qt = w & 1;
        int jl = qt * 16 + lr;
        unsigned lpk0 = 0, lpk1 = 0;
        for (int it = 0; it < 3; it++) {
            int kbase = (2 * it + kh) * 16 + quad * 4;
            for (int r = 0; r < 4; r++) {
                int kk = kbase + r;
                int r30 = (kk >= 60) ? 2 : (kk >= 30 ? 1 : 0);
                int cm  = kk - r30 * 30;
                int d   = cm - jl;
                int gi  = i - 1 + r30, gj = j0 - 1 + cm;
                bool vld = (kk < NLOC) & ((unsigned)d <= 2u)
                         & (gi >= 0) & (gi < WID) & (gj >= 0) & (gj < WID);
                unsigned nib = vld ? (unsigned)(r30 * 3 + d) : 15u;
                if (it < 2) lpk0 |= nib << ((it * 4 + r) * 4);
                else        lpk1 |= nib << (r * 4);
            }
        }
        lmask[pos * 256 + tid] = make_uint2(lpk0, lpk1);
    } else {
        int idx = (bid - 1274) * 1024 + tid * 4;   // zero xpa (100352 floats)
        *reinterpret_cast<float4*>(&xpa[idx]) = make_float4(0.f, 0.f, 0.f, 0.f);
    }
}

// ---------------------------------------------------------------------------
// LayerNorm of the (pre-pooled by gemm1 atomics) xpa -> fp32 xp.
// Blocks >= 392: pb gather.
// ---------------------------------------------------------------------------
__global__ __launch_bounds__(256) void pool_ln(
    const float* __restrict__ xpa, const float* __restrict__ g,
    const float* __restrict__ bb, float* __restrict__ xp,
    const float* __restrict__ tab, const int* __restrict__ rpi,
    float* __restrict__ pb)
{
    if (blockIdx.x >= 392) {
        int gg = (blockIdx.x - 392) * 256 + threadIdx.x;
        if (gg >= NSEQ * PLEN) return;
        int idx = rpi[gg];
        const float* src = &tab[(size_t)idx * 8];
        float4 a = *reinterpret_cast<const float4*>(src);
        float4 bq = *reinterpret_cast<const float4*>(src + 4);
        *reinterpret_cast<float4*>(&pb[(size_t)gg * 8])     = a;
        *reinterpret_cast<float4*>(&pb[(size_t)gg * 8 + 4]) = bq;
        return;
    }
    int c = threadIdx.x;
    float s = xpa[(size_t)blockIdx.x * CDIM + c];

    float ssum = s, ssq = s * s;
    #pragma unroll
    for (int m = 32; m > 0; m >>= 1) {
        ssum += __shfl_xor(ssum, m);
        ssq  += __shfl_xor(ssq, m);
    }
    __shared__ float r1[4], r2[4];
    int wv = threadIdx.x >> 6;
    if ((threadIdx.x & 63) == 0) { r1[wv] = ssum; r2[wv] = ssq; }
    __syncthreads();
    float tsum = r1[0] + r1[1] + r1[2] + r1[3];
    float tsq  = r2[0] + r2[1] + r2[2] + r2[3];
    float mu  = tsum * (1.f / 256.f);
    float var = tsq * (1.f / 256.f) - mu * mu;
    float o = (s - mu) * rsqrtf(var + 1e-5f) * g[c] + bb[c];
    xp[(size_t)blockIdx.x * CDIM + c] = o;
}

// ---------------------------------------------------------------------------
// fp32 kvp GEMM (M=392, N=512, K=256) + pwt transpose on the extra grid row.
// ---------------------------------------------------------------------------
__global__ __launch_bounds__(256) void kvp_pwt(
    const float* __restrict__ A, const float* __restrict__ Bw,
    const float* __restrict__ bias, float* __restrict__ C,
    const float* __restrict__ pw, unsigned short* __restrict__ pwt)
{
    if (blockIdx.y == 7) {
        int base = blockIdx.x * 256 + threadIdx.x;   // 0..2047
        for (int t = base; t < 65536; t += 2048) {
            int n = t >> 8, k = t & 255;
            pwt[t] = f2bf(pw[k * 256 + n]);
        }
        return;
    }
    const int M = BATCH * PLEN, N = 512, K = 256;
    __shared__ float Asm[16][68];
    __shared__ float Bsm[16][68];
    const int tid = threadIdx.x;
    const int tx  = tid & 15, ty = tid >> 4;
    const int bm  = blockIdx.y * 64, bn = blockIdx.x * 64;
    float acc[4][4] = {};

    const int am  = tid >> 2;
    const int ak  = (tid & 3) * 4;
    const int bk  = tid >> 4;
    const int bn4 = (tid & 15) * 4;

    for (int k0 = 0; k0 < K; k0 += 16) {
        float4 av = make_float4(0.f, 0.f, 0.f, 0.f);
        if (bm + am < M)
            av = *reinterpret_cast<const float4*>(&A[(size_t)(bm + am) * K + k0 + ak]);
        Asm[ak+0][am] = av.x; Asm[ak+1][am] = av.y; Asm[ak+2][am] = av.z; Asm[ak+3][am] = av.w;

        float4 bv = *reinterpret_cast<const float4*>(&Bw[(size_t)(k0 + bk) * N + bn + bn4]);
        Bsm[bk][bn4+0] = bv.x; Bsm[bk][bn4+1] = bv.y; Bsm[bk][bn4+2] = bv.z; Bsm[bk][bn4+3] = bv.w;
        __syncthreads();

        #pragma unroll
        for (int kk = 0; kk < 16; kk++) {
            float a0 = Asm[kk][ty*4+0], a1 = Asm[kk][ty*4+1], a2 = Asm[kk][ty*4+2], a3 = Asm[kk][ty*4+3];
            float b0 = Bsm[kk][tx*4+0], b1 = Bsm[kk][tx*4+1], b2 = Bsm[kk][tx*4+2], b3 = Bsm[kk][tx*4+3];
            acc[0][0] += a0*b0; acc[0][1] += a0*b1; acc[0][2] += a0*b2; acc[0][3] += a0*b3;
            acc[1][0] += a1*b0; acc[1][1] += a1*b1; acc[1][2] += a1*b2; acc[1][3] += a1*b3;
            acc[2][0] += a2*b0; acc[2][1] += a2*b1; acc[2][2] += a2*b2; acc[2][3] += a2*b3;
            acc[3][0] += a3*b0; acc[3][1] += a3*b1; acc[3][2] += a3*b2; acc[3][3] += a3*b3;
        }
        __syncthreads();
    }

    const int n0 = bn + tx * 4;
    float4 bsv = *reinterpret_cast<const float4*>(&bias[n0]);
    #pragma unroll
    for (int r = 0; r < 4; r++) {
        int m = bm + ty * 4 + r;
        if (m < M) {
            float4 o;
            o.x = acc[r][0] + bsv.x;
            o.y = acc[r][1] + bsv.y;
            o.z = acc[r][2] + bsv.z;
            o.w = acc[r][3] + bsv.w;
            *reinterpret_cast<float4*>(&C[(size_t)m * N + n0]) = o;
        }
    }
}

// ---------------------------------------------------------------------------
// MFMA fused attention, R13: R12 + ltS transposed to [nib][jl] stride 33
// (+1 pad) — fixes the 16-way bank conflict of the [jl][nib] layout where
// the hot nib=15 lane-majority all landed on banks 15/31.
// ---------------------------------------------------------------------------
__global__ __launch_bounds__(256, 6) void attn_tile(
    const float* __restrict__ qn,   // (B,N,256)  L2-normalized q
    const float* __restrict__ kvb,  // (B,N,512)  [k normalized | v]
    const float* __restrict__ kvp,  // (B,49,512) [k_pool UNnormalized | v_pool]
    const float* __restrict__ pb,   // (N,49,8)   pool bias gathered
    const float* __restrict__ scaleT, // (8)
    const float* __restrict__ corrT,  // (8,9)
    const float* __restrict__ ltT,    // (8,9,32)
    const float* __restrict__ qe,   // (8,32)
    const float* __restrict__ rpb,  // (8,9)
    const uint2* __restrict__ lmask,// (112,256) packed band nibbles
    unsigned short* __restrict__ ab)// (B,N,256) bf16 out
{
    __shared__ char sm[25920];
    _Float16*  KlocH = (_Float16*)(sm);            // [96][40] fp16   7680  (A)
    _Float16*  KlocL = (_Float16*)(sm + 7680);     // [96][40] fp16   7680  (A)
    _Float16*  Khi   = (_Float16*)(sm + 15360);    // [64][40] fp16   5120  (A)
    _Float16*  Qhi   = (_Float16*)(sm + 20480);    // [32][40] fp16   2560  (A)
    _Float16*  Qlo   = (_Float16*)(sm + 23040);    // [32][40] fp16   2560  (A end 25600)
    _Float16*  Aall  = (_Float16*)(sm);            // [32][KT] fp16  10752  (B)
    _Float16*  VT    = (_Float16*)(sm + 10752);    // [32][KT] fp16  10752  (B end 21504)
    float*     ltS   = (float*)(sm + 21504);       // [16][33] fp32   2112  (aliased, post-S2)
    float*     psum  = (float*)(sm + 25600);       // [4][16] fp32     256  (static)
    float*     erpbS = (float*)(sm + 25856);       // [16] fp32         64  (static)

    const int tid  = threadIdx.x;
    const int w    = tid >> 6, lane = tid & 63;
    const int lr   = lane & 15, quad = lane >> 4;
    const int q8   = quad * 8;
    const int bid  = blockIdx.x;
    const int half = bid & 1;
    const int rest = bid >> 1;
    const int i    = rest % WID;
    const int h    = (rest / WID) & 7;
    const int b    = rest / (WID * NHEADS);
    const int j0   = half * TJ;

    const int kh = w >> 1;          // key half (tiles 2*it+kh)
    const int qt = w & 1;           // query tile
    const int jl = qt * 16 + lr;    // this lane's query row (0..31)

    const float scale = scaleT[h];
    const float inv = 1.0f / scale;

    // ---- band-mask nibbles (precomputed, (b,h)-invariant) ----
    const uint2 lm = lmask[(i * 2 + half) * 256 + tid];

    // ---- erpbS: exp(rpb) table, slot 15 (and 9..14) = 0 ----
    if (tid < 16) erpbS[tid] = (tid < 9) ? __expf(rpb[h * 9 + tid]) : 0.f;

    // ---- T14: issue first-iteration V loads NOW (consumed post-S2) ----
    float4 va0, vb0; bool v0a, v1a;
    {
        int p = tid >> 3, d4 = tid & 7;
        int kk0 = 2 * p;
        int r = kk0 / 30, c0 = kk0 % 30;
        int gi = i - 1 + r;
        int gj0 = j0 - 1 + c0, gj1 = gj0 + 1;
        v0a = (gi >= 0) & (gi < WID) & (gj0 >= 0) & (gj0 < WID);
        v1a = (gi >= 0) & (gi < WID) & (gj1 >= 0) & (gj1 < WID);
        int gic  = min(max(gi, 0), WID - 1);
        int gj0c = min(max(gj0, 0), WID - 1), gj1c = min(max(gj1, 0), WID - 1);
        va0 = *reinterpret_cast<const float4*>(
            &kvb[((size_t)(b * NSEQ + gic * WID + gj0c)) * 512 + 256 + h * HDIM + d4 * 4]);
        vb0 = *reinterpret_cast<const float4*>(
            &kvb[((size_t)(b * NSEQ + gic * WID + gj1c)) * 512 + 256 + h * HDIM + d4 * 4]);
    }
    float4 vp0;
    {
        int m = tid >> 3, d4 = tid & 7;
        vp0 = *reinterpret_cast<const float4*>(
            &kvp[((size_t)(b * PLEN + m)) * 512 + 256 + h * HDIM + d4 * 4]);
    }

    // ---- prefetch pool biases for this lane's pool regs (tiles it=3,4) ----
    float pbr[2][4];
    #pragma unroll
    for (int it = 0; it < 2; it++) {
        int kt = 6 + 2 * it + kh;
        int pbase = (kt - 6) * 16 + quad * 4;
        #pragma unroll
        for (int r = 0; r < 4; r++) {
            int p = pbase + r;
            float bv = 0.f;
            if (p < PLEN && jl < TJ) {
                int n = i * WID + j0 + jl;
                bv = pb[((size_t)n * PLEN + p) * 8 + h];
            }
            pbr[it][r] = bv;
        }
    }

    // ---- stage scaled q (hi/lo fp16), zero-pad rows 28..31 ----
    if (tid < 224) {
        int ql_ = tid >> 3, d4 = tid & 7;
        int n  = i * WID + j0 + ql_;
        float4 qv = *reinterpret_cast<const float4*>(&qn[((size_t)(b * NSEQ + n)) * CDIM + h * HDIM + d4 * 4]);
        float4 ev = *reinterpret_cast<const float4*>(&qe[h * HDIM + d4 * 4]);
        float sx = (qv.x + ev.x) * scale, sy = (qv.y + ev.y) * scale;
        float sz = (qv.z + ev.z) * scale, sw = (qv.w + ev.w) * scale;
        half4_t hv = { (_Float16)sx, (_Float16)sy, (_Float16)sz, (_Float16)sw };
        half4_t lv = { (_Float16)(sx - (float)hv.x), (_Float16)(sy - (float)hv.y),
                       (_Float16)(sz - (float)hv.z), (_Float16)(sw - (float)hv.w) };
        *reinterpret_cast<half4_t*>(&Qhi[ql_ * 40 + d4 * 4]) = hv;
        *reinterpret_cast<half4_t*>(&Qlo[ql_ * 40 + d4 * 4]) = lv;
    } else {
        int t = tid - 224;
        int ql_ = 28 + (t >> 3), d4 = t & 7;
        half4_t z = {};
        *reinterpret_cast<half4_t*>(&Qhi[ql_ * 40 + d4 * 4]) = z;
        *reinterpret_cast<half4_t*>(&Qlo[ql_ * 40 + d4 * 4]) = z;
    }

    // ---- stage Khi [64 rows]: pool k (normalized) 0..48 | ltT 49..57 | zero
    for (int idx = tid; idx < 64 * 8; idx += 256) {
        int c = idx >> 3, d4 = idx & 7;
        half4_t hv;
        if (c < PLEN) {
            float4 k4 = *reinterpret_cast<const float4*>(&kvp[((size_t)(b * PLEN + c)) * 512 + h * HDIM + d4 * 4]);
            float ss2 = k4.x * k4.x + k4.y * k4.y + k4.z * k4.z + k4.w * k4.w;
            ss2 += __shfl_xor(ss2, 1); ss2 += __shfl_xor(ss2, 2); ss2 += __shfl_xor(ss2, 4);
            float rn = 1.0f / fmaxf(sqrtf(ss2), 1e-12f);
            hv.x = (_Float16)(k4.x * rn); hv.y = (_Float16)(k4.y * rn);
            hv.z = (_Float16)(k4.z * rn); hv.w = (_Float16)(k4.w * rn);
        } else if (c < 58) {
            int t = c - PLEN;
            float4 l4 = *reinterpret_cast<const float4*>(&ltT[((size_t)h * 9 + t) * 32 + d4 * 4]);
            hv.x = (_Float16)l4.x; hv.y = (_Float16)l4.y;
            hv.z = (_Float16)l4.z; hv.w = (_Float16)l4.w;
        } else {
            hv = half4_t{};
        }
        *reinterpret_cast<half4_t*>(&Khi[c * 40 + d4 * 4]) = hv;
    }

    // ---- stage local k as fp16 hi/lo ----
    for (int idx = tid; idx < NLOC * 8; idx += 256) {
        int kk = idx >> 3, d4 = idx & 7;
        int r = kk / 30, c = kk % 30;
        int gi = i - 1 + r, gj = j0 - 1 + c;
        int gic = min(max(gi, 0), WID - 1), gjc = min(max(gj, 0), WID - 1);
        float4 k4 = *reinterpret_cast<const float4*>(
            &kvb[((size_t)(b * NSEQ + gic * WID + gjc)) * 512 + h * HDIM + d4 * 4]);
        half4_t hv = { (_Float16)k4.x, (_Float16)k4.y, (_Float16)k4.z, (_Float16)k4.w };
        half4_t lv = { (_Float16)(k4.x - (float)hv.x), (_Float16)(k4.y - (float)hv.y),
                       (_Float16)(k4.z - (float)hv.z), (_Float16)(k4.w - (float)hv.w) };
        *reinterpret_cast<half4_t*>(&KlocH[kk * 40 + d4 * 4]) = hv;
        *reinterpret_cast<half4_t*>(&KlocL[kk * 40 + d4 * 4]) = lv;
    }
    // zero pad rows 90..95
    if (tid < 48) {
        int kk = 90 + (tid >> 3), d4 = tid & 7;
        half4_t z = {};
        *reinterpret_cast<half4_t*>(&KlocH[kk * 40 + d4 * 4]) = z;
        *reinterpret_cast<half4_t*>(&KlocL[kk * 40 + d4 * 4]) = z;
    }
    __syncthreads();   // S1

    // ================= transposed score MFMAs: C[key][query] =================
    half8 qh = *reinterpret_cast<const half8*>(&Qhi[jl * 40 + q8]);
    half8 qlo = *reinterpret_cast<const half8*>(&Qlo[jl * 40 + q8]);
    f32x4 c5[5];
    __builtin_amdgcn_s_setprio(1);
    #pragma unroll
    for (int it = 0; it < 3; it++) {        // local tiles (kt = 2*it+kh < 6)
        int kt = 2 * it + kh;
        half8 ah = *reinterpret_cast<const half8*>(&KlocH[(kt * 16 + lr) * 40 + q8]);
        half8 al = *reinterpret_cast<const half8*>(&KlocL[(kt * 16 + lr) * 40 + q8]);
        f32x4 c = {};
        c = __builtin_amdgcn_mfma_f32_16x16x32_f16(ah, qh, c, 0, 0, 0);
        c = __builtin_amdgcn_mfma_f32_16x16x32_f16(ah, qlo, c, 0, 0, 0);
        c = __builtin_amdgcn_mfma_f32_16x16x32_f16(al, qh, c, 0, 0, 0);
        c5[it] = c;
    }
    #pragma unroll
    for (int it = 3; it < 5; it++) {        // pool tiles (kt >= 6)
        int kt = 2 * it + kh;
        half8 kf = *reinterpret_cast<const half8*>(&Khi[((kt - 6) * 16 + lr) * 40 + q8]);
        f32x4 c = {};
        c = __builtin_amdgcn_mfma_f32_16x16x32_f16(kf, qh, c, 0, 0, 0);
        c = __builtin_amdgcn_mfma_f32_16x16x32_f16(kf, qlo, c, 0, 0, 0);
        c5[it] = c;
    }
    __builtin_amdgcn_s_setprio(0);

    // ===== in-register exp (mask via erpbS multiply) + partial sum =====
    float pe[5][4];
    float pp = 0.f;
    #pragma unroll
    for (int it = 0; it < 3; it++) {        // local
        #pragma unroll
        for (int r = 0; r < 4; r++) {
            unsigned nib = (it < 2) ? ((lm.x >> ((it * 4 + r) * 4)) & 15u)
                                    : ((lm.y >> (r * 4)) & 15u);
            float v = __expf(c5[it][r]) * erpbS[nib];
            pe[it][r] = v; pp += v;
        }
    }
    #pragma unroll
    for (int it = 3; it < 5; it++) {        // pool
        int kt = 2 * it + kh;
        int pbase = (kt - 6) * 16 + quad * 4;
        #pragma unroll
        for (int r = 0; r < 4; r++) {
            int p = pbase + r;
            float v = 0.f;
            if (p < PLEN) v = __expf(c5[it][r] + pbr[it - 3][r]);
            pe[it][r] = v; pp += v;
        }
    }
    pp += __shfl_xor(pp, 16);
    pp += __shfl_xor(pp, 32);
    if (lane < 16) psum[w * 16 + lr] = pp;
    __syncthreads();   // S2 — phase-A LDS dead; psum visible

    // ===== post-S2: lt extras to ltS[nib][jl] stride 33 (kh==1, tile 9) =====
    if (kh == 1) {
        #pragma unroll
        for (int r = 0; r < 4; r++) {
            int p = 48 + quad * 4 + r;      // tile 9: key 144+quad*4+r
            int e = p - 49;                 // -1..14
            bool real = (e >= 0) & (e < 9);
            float val = real ? (c5[4][r] * inv + corrT[h * 9 + e]) : 0.f;
            int slot = real ? e : ((e < 0) ? 15 : e);
            ltS[slot * 33 + jl] = val;
        }
    }

    // ===== V_T writes: prefetched iter0 + inline tails =====
    {
        int p = tid >> 3, d4 = tid & 7;
        int kk0 = 2 * p;
        if (!v0a) va0 = make_float4(0.f, 0.f, 0.f, 0.f);
        if (!v1a) vb0 = make_float4(0.f, 0.f, 0.f, 0.f);
        half2_t p0 = { (_Float16)va0.x, (_Float16)vb0.x };
        half2_t p1 = { (_Float16)va0.y, (_Float16)vb0.y };
        half2_t p2 = { (_Float16)va0.z, (_Float16)vb0.z };
        half2_t p3 = { (_Float16)va0.w, (_Float16)vb0.w };
        *reinterpret_cast<half2_t*>(&VT[(d4 * 4 + 0) * KT + kk0]) = p0;
        *reinterpret_cast<half2_t*>(&VT[(d4 * 4 + 1) * KT + kk0]) = p1;
        *reinterpret_cast<half2_t*>(&VT[(d4 * 4 + 2) * KT + kk0]) = p2;
        *reinterpret_cast<half2_t*>(&VT[(d4 * 4 + 3) * KT + kk0]) = p3;
    }
    if (tid < 104) {                         // local tail: idx = tid + 256
        int idx = tid + 256;
        int p = idx >> 3, d4 = idx & 7;
        int kk0 = 2 * p;
        int r = kk0 / 30, c0 = kk0 % 30;
        int gi = i - 1 + r;
        int gj0 = j0 - 1 + c0, gj1 = gj0 + 1;
        bool v0 = (gi >= 0) & (gi < WID) & (gj0 >= 0) & (gj0 < WID);
        bool v1 = (gi >= 0) & (gi < WID) & (gj1 >= 0) & (gj1 < WID);
        int gic  = min(max(gi, 0), WID - 1);
        int gj0c = min(max(gj0, 0), WID - 1), gj1c = min(max(gj1, 0), WID - 1);
        float4 va = *reinterpret_cast<const float4*>(
            &kvb[((size_t)(b * NSEQ + gic * WID + gj0c)) * 512 + 256 + h * HDIM + d4 * 4]);
        float4 vb = *reinterpret_cast<const float4*>(
            &kvb[((size_t)(b * NSEQ + gic * WID + gj1c)) * 512 + 256 + h * HDIM + d4 * 4]);
        if (!v0) va = make_float4(0.f, 0.f, 0.f, 0.f);
        if (!v1) vb = make_float4(0.f, 0.f, 0.f, 0.f);
        half2_t p0 = { (_Float16)va.x, (_Float16)vb.x };
        half2_t p1 = { (_Float16)va.y, (_Float16)vb.y };
        half2_t p2 = { (_Float16)va.z, (_Float16)vb.z };
        half2_t p3 = { (_Float16)va.w, (_Float16)vb.w };
        *reinterpret_cast<half2_t*>(&VT[(d4 * 4 + 0) * KT + kk0]) = p0;
        *reinterpret_cast<half2_t*>(&VT[(d4 * 4 + 1) * KT + kk0]) = p1;
        *reinterpret_cast<half2_t*>(&VT[(d4 * 4 + 2) * KT + kk0]) = p2;
        *reinterpret_cast<half2_t*>(&VT[(d4 * 4 + 3) * KT + kk0]) = p3;
    }
    {                                        // pool iter0 (prefetched)
        int m = tid >> 3, d4 = tid & 7;
        VT[(d4 * 4 + 0) * KT + 96 + m] = (_Float16)vp0.x;
        VT[(d4 * 4 + 1) * KT + 96 + m] = (_Float16)vp0.y;
        VT[(d4 * 4 + 2) * KT + 96 + m] = (_Float16)vp0.z;
        VT[(d4 * 4 + 3) * KT + 96 + m] = (_Float16)vp0.w;
    }
    if (tid < 136) {                         // pool tail: idx = tid + 256
        int idx = tid + 256;
        int m = idx >> 3, d4 = idx & 7;
        float4 v4 = *reinterpret_cast<const float4*>(
            &kvp[((size_t)(b * PLEN + m)) * 512 + 256 + h * HDIM + d4 * 4]);
        VT[(d4 * 4 + 0) * KT + 96 + m] = (_Float16)v4.x;
        VT[(d4 * 4 + 1) * KT + 96 + m] = (_Float16)v4.y;
        VT[(d4 * 4 + 2) * KT + 96 + m] = (_Float16)v4.z;
        VT[(d4 * 4 + 3) * KT + 96 + m] = (_Float16)v4.w;
    }
    // zero VT pad cols (90..95, 145..159)
    for (int idx = tid; idx < 32 * 6; idx += 256) {
        int d = idx / 6, c = idx % 6;
        VT[d * KT + 90 + c] = (_Float16)0.f;
    }
    for (int idx = tid; idx < 32 * 15; idx += 256) {
        int d = idx / 15, c = idx % 15;
        VT[d * KT + 145 + c] = (_Float16)0.f;
    }
    __syncthreads();   // S2b — ltS visible; VT done

    // ===== normalize + lt-extra (transposed ltS read) + scatter =====
    {
        float tot = psum[qt * 16 + lr] + psum[qt * 16 + 32 + lr];
        float rtot = 1.0f / tot;
        #pragma unroll
        for (int it = 0; it < 3; it++) {    // local tiles
            int kt = 2 * it + kh;
            int kbase = kt * 16 + quad * 4;
            float a[4];
            #pragma unroll
            for (int r = 0; r < 4; r++) {
                unsigned nib = (it < 2) ? ((lm.x >> ((it * 4 + r) * 4)) & 15u)
                                        : ((lm.y >> (r * 4)) & 15u);
                a[r] = pe[it][r] * rtot + ltS[nib * 33 + jl];
            }
            half2_t h01 = { (_Float16)a[0], (_Float16)a[1] };
            half2_t h23 = { (_Float16)a[2], (_Float16)a[3] };
            *reinterpret_cast<half2_t*>(&Aall[jl * KT + kbase])     = h01;
            *reinterpret_cast<half2_t*>(&Aall[jl * KT + kbase + 2]) = h23;
        }
        #pragma unroll
        for (int it = 3; it < 5; it++) {    // pool tiles
            int kt = 2 * it + kh;
            int kbase = kt * 16 + quad * 4;
            half2_t h01 = { (_Float16)(pe[it][0] * rtot), (_Float16)(pe[it][1] * rtot) };
            half2_t h23 = { (_Float16)(pe[it][2] * rtot), (_Float16)(pe[it][3] * rtot) };
            *reinterpret_cast<half2_t*>(&Aall[jl * KT + kbase])     = h01;
            *reinterpret_cast<half2_t*>(&Aall[jl * KT + kbase + 2]) = h23;
        }
    }
    __syncthreads();   // S3

    // ================= unified AV via MFMA, direct bf16 store ===============
    {
        int mt = w >> 1, nt = w & 1;
        f32x4 c = {};
        __builtin_amdgcn_s_setprio(1);
        #pragma unroll
        for (int kk = 0; kk < 5; kk++) {
            half8 af = *reinterpret_cast<const half8*>(&Aall[(mt * 16 + lr) * KT + kk * 32 + q8]);
            half8 bv = *reinterpret_cast<const half8*>(&VT[(nt * 16 + lr) * KT + kk * 32 + q8]);
            c = __builtin_amdgcn_mfma_f32_16x16x32_f16(af, bv, c, 0, 0, 0);
        }
        __builtin_amdgcn_s_setprio(0);
        int dim = nt * 16 + lr;
        #pragma unroll
        for (int r = 0; r < 4; r++) {
            int pr = mt * 16 + quad * 4 + r;
            if (pr < TJ) {
                int n = i * WID + j0 + pr;
                ab[((size_t)(b * NSEQ + n)) * CDIM + h * HDIM + dim] = f2bf(c[r]);
            }
        }
    }
}

// ---------------------------------------------------------------------------
// Workspace (floats), total 26,023,936 = 104.1 MB (unchanged):
//   qn @0 | kvbuf @6422528 | xs @19267584 | xp @25690112 (fp32)
//   kvp @25790464 | tab @25991168
// xs region: ab bf16 [0:3211264) halfs; pwt bf16 at float offset 3211264;
//   xpa fp32 accumulator at xs + 4000000 (100352 floats).
// d_out scratch until proj:
//   wcat halfs at float 3211264 | scaleT @3420000 | corrT @3420016 |
//   ltT @3420100 | pb @3500000 | lmask @4800000
// ---------------------------------------------------------------------------
extern "C" void kernel_launch(void* const* d_in, const int* in_sizes, int n_in,
                              void* d_out, int out_size, void* d_ws, size_t ws_size,
                              hipStream_t stream)
{
    const float* x    = (const float*)d_in[0];
    const float* sls  = (const float*)d_in[1];
    const float* rct  = (const float*)d_in[2];
    const float* q_w  = (const float*)d_in[3];
    const float* q_b  = (const float*)d_in[4];
    const float* qe   = (const float*)d_in[5];
    const float* temp = (const float*)d_in[6];
    const float* kv_w = (const float*)d_in[7];
    const float* kv_b = (const float*)d_in[8];
    const float* sr_w = (const float*)d_in[9];
    const float* sr_b = (const float*)d_in[10];
    const float* ng   = (const float*)d_in[11];
    const float* nb   = (const float*)d_in[12];
    const float* f1w  = (const float*)d_in[13];
    const float* f1b  = (const float*)d_in[14];
    const float* f2w  = (const float*)d_in[15];
    const float* f2b  = (const float*)d_in[16];
    const float* rpb  = (const float*)d_in[17];
    const float* lt   = (const float*)d_in[18];
    const float* lb   = (const float*)d_in[19];
    const float* pw   = (const float*)d_in[20];
    const float* pbi  = (const float*)d_in[21];
    const int*   rpi  = (const int*)d_in[22];

    if (ws_size < (size_t)26023936 * sizeof(float)) return;

    float* ws  = (float*)d_ws;
    float* qn  = ws;
    float* kvbuf = ws + 6422528;
    float* xs  = ws + 19267584;
    float* xp  = ws + 25690112;
    float* kvp = ws + 25790464;
    float* tab = ws + 25991168;
    float* out = (float*)d_out;

    unsigned short* ab   = (unsigned short*)xs;                  // bf16 attn out
    unsigned short* pwt  = (unsigned short*)(xs + 3211264);      // bf16 proj w^T
    float* xpa = xs + 4000000;                                   // pooled-acc
    unsigned short* wcat = (unsigned short*)(out + 3211264);     // bf16 [q|kv|sr]^T
    float* scaleT = out + 3420000;
    float* corrT  = out + 3420016;
    float* ltT    = out + 3420100;
    float* pbt    = out + 3500000;
    uint2* lmaskT = (uint2*)(out + 4800000);

    dim3 blk(256);

    // prep: wcat, cpb table, tables, lmask, zero xpa (one launch)
    prep_misc<<<1372, blk, 0, stream>>>(q_w, kv_w, sr_w, wcat,
                                        rct, f1w, f1b, f2w, f2b, tab,
                                        temp, sls, qe, lt, lb,
                                        scaleT, corrT, ltT, lmaskT, xpa);

    // fused q|kv|sr MFMA GEMM, fp32-A staging, fused L2-norm epilogue,
    // sr segment: gelu + fused 8x8 pooling into xpa (atomics)
    gemm_bt<1, 1><<<dim3(8, 196), blk, 0, stream>>>(x, wcat, q_b, kv_b, sr_b,
                                                    qn, kvbuf, xs, xpa);

    // LayerNorm of pooled xpa -> fp32 xp; blocks >= 392 do the pb gather
    pool_ln<<<993, blk, 0, stream>>>(xpa, ng, nb, xp, tab, rpi, pbt);

    // pooled kv projection (fp32) + pwt transpose on extra grid row
    kvp_pwt<<<dim3(8, 8), blk, 0, stream>>>(xp, kv_w, kv_b, kvp, pw, pwt);

    // fused attention -> bf16 ab
    attn_tile<<<BATCH * NHEADS * WID * 2, blk, 0, stream>>>(
        qn, kvbuf, kvp, pbt, scaleT, corrT, ltT, qe, rpb, lmaskT, ab);

    // output projection (MFMA, no norm, bf16 A)
    gemm_bt<0, 0><<<dim3(2, 196), blk, 0, stream>>>(ab, pwt, pbi, pbi, pbi,
                                                    out, out, out, nullptr);
}

// Round 7
// 289.113 us; speedup vs baseline: 1.1054x; 1.1054x over previous
//
#include <hip/hip_runtime.h>
#include <math.h>

#define NSEQ   3136      // N0 = 56*56
#define NTOK   25088     // B * NSEQ
#define BATCH  8
#define WID    56
#define NHEADS 8
#define HDIM   32
#define CDIM   256
#define PLEN   49
#define NEGC  -1000000000.0f

#define TJ     28        // pixels per block (half an image row)
#define NLOC   90        // 3 rows x 30 cols of local keys
#define KT     168       // A_all / V_T stride in halfs (160 keys + pad)

typedef __attribute__((ext_vector_type(8))) short short8;
typedef __attribute__((ext_vector_type(4))) float f32x4;
typedef __attribute__((ext_vector_type(8))) _Float16 half8;
typedef __attribute__((ext_vector_type(4))) _Float16 half4_t;
typedef __attribute__((ext_vector_type(2))) _Float16 half2_t;

__device__ __forceinline__ float gelu_exact(float x) {
    return 0.5f * x * (1.0f + erff(x * 0.70710678118654752440f));
}

__device__ __forceinline__ unsigned short f2bf(float f) {
    unsigned int u = __float_as_uint(f);
    u += 0x7fffu + ((u >> 16) & 1u);
    return (unsigned short)(u >> 16);
}

__device__ __forceinline__ void gl_lds16(const void* g, void* l) {
    __builtin_amdgcn_global_load_lds(
        (const __attribute__((address_space(1))) void*)g,
        (__attribute__((address_space(3))) void*)l, 16, 0, 0);
}

// ---------------------------------------------------------------------------
// bf16 MFMA GEMM (m97 structure), segmented epilogue with fused per-head
// L2-norm. AF32=1: A fp32 staged via gl_lds with XOR-swizzle (inverse
// swizzle folded into the global source column), cvt to bf16 at fragment
// read (v_cvt_pk_bf16_f32, RNE == f2bf). XCD-chunked blockIdx swizzle.
// R7: atomic pooling REVERTED (R6 post-mortem: 64-way atomic fan-in
// serialized gemm1 45->96us). sr segment stores gelu output to xs.
// ---------------------------------------------------------------------------
template<int NORM, int AF32>
__global__ __launch_bounds__(256) void gemm_bt(
    const void* __restrict__ Araw,
    const unsigned short* __restrict__ Bt,
    const float* __restrict__ b0, const float* __restrict__ b1,
    const float* __restrict__ b2,
    float* __restrict__ o0, float* __restrict__ o1, float* __restrict__ o2)
{
    __shared__ char AsBuf[AF32 ? 16384 : 8192];
    __shared__ short Bs[4096];
    const int tid = threadIdx.x;
    const int w = tid >> 6, lane = tid & 63;

    // XCD-chunked swizzle: 8 consecutive chunks of the grid -> 8 XCDs.
    const int nwg = gridDim.x * gridDim.y;
    const int id  = blockIdx.y * gridDim.x + blockIdx.x;
    const int swz = (id & 7) * (nwg >> 3) + (id >> 3);
    const int bm = (swz / gridDim.x) * 128;
    const int bn = (swz % gridDim.x) * 128;

    const int m0 = (w >> 1) * 64, n0 = (w & 1) * 64;
    const int lr = lane & 15, q8 = (lane >> 4) * 8, quad = lane >> 4;

    f32x4 acc[4][4] = {};

    char* bB = (char*)Bs + w * 1024;
    const unsigned short* Bp0 = Bt + (size_t)(bn + (tid >> 2)) * 256 + (tid & 3) * 8;
    const unsigned short* Bp1 = Bt + (size_t)(bn + (tid >> 2) + 64) * 256 + (tid & 3) * 8;

    // A staging pointers
    const unsigned short* Ap0b; const unsigned short* Ap1b;
    const float *Af0, *Af1, *Af2, *Af3;
    char* aB;
    if constexpr (AF32) {
        const float* Af = (const float*)Araw;
        const int r8 = tid >> 3;                       // rel row 0..31
        const int xc = ((tid & 7) ^ (r8 & 7)) * 4;     // inverse-swizzled col
        Af0 = Af + (size_t)(bm + r8      ) * 256 + xc;
        Af1 = Af + (size_t)(bm + r8 + 32 ) * 256 + xc;
        Af2 = Af + (size_t)(bm + r8 + 64 ) * 256 + xc;
        Af3 = Af + (size_t)(bm + r8 + 96 ) * 256 + xc;
        aB = (char*)AsBuf + w * 1024;
    } else {
        const unsigned short* Ab = (const unsigned short*)Araw;
        Ap0b = Ab + (size_t)(bm + (tid >> 2)) * 256 + (tid & 3) * 8;
        Ap1b = Ab + (size_t)(bm + (tid >> 2) + 64) * 256 + (tid & 3) * 8;
        aB = (char*)AsBuf + w * 1024;
    }

    for (int k0 = 0; k0 < 256; k0 += 32) {
        if (k0) __syncthreads();
        if constexpr (AF32) {
            gl_lds16(Af0 + k0, aB);
            gl_lds16(Af1 + k0, aB + 4096);
            gl_lds16(Af2 + k0, aB + 8192);
            gl_lds16(Af3 + k0, aB + 12288);
        } else {
            gl_lds16(Ap0b + k0, aB);
            gl_lds16(Ap1b + k0, aB + 4096);
        }
        gl_lds16(Bp0 + k0, bB);
        gl_lds16(Bp1 + k0, bB + 4096);
        __syncthreads();
        short8 af[4], bf[4];
        if constexpr (AF32) {
            const char* Ab = (const char*)AsBuf;
            #pragma unroll
            for (int t = 0; t < 4; t++) {
                int R = m0 + t * 16 + lr;
                int c0b = R * 128 + ((((quad << 1) | 0) ^ (R & 7)) << 4);
                int c1b = R * 128 + ((((quad << 1) | 1) ^ (R & 7)) << 4);
                f32x4 x0 = *reinterpret_cast<const f32x4*>(Ab + c0b);
                f32x4 x1 = *reinterpret_cast<const f32x4*>(Ab + c1b);
                union { int i4[4]; short8 s8; } u;
                asm("v_cvt_pk_bf16_f32 %0, %1, %2" : "=v"(u.i4[0]) : "v"(x0[0]), "v"(x0[1]));
                asm("v_cvt_pk_bf16_f32 %0, %1, %2" : "=v"(u.i4[1]) : "v"(x0[2]), "v"(x0[3]));
                asm("v_cvt_pk_bf16_f32 %0, %1, %2" : "=v"(u.i4[2]) : "v"(x1[0]), "v"(x1[1]));
                asm("v_cvt_pk_bf16_f32 %0, %1, %2" : "=v"(u.i4[3]) : "v"(x1[2]), "v"(x1[3]));
                af[t] = u.s8;
            }
        } else {
            const short* As16 = (const short*)AsBuf;
            #pragma unroll
            for (int t = 0; t < 4; t++)
                af[t] = *reinterpret_cast<const short8*>(&As16[(m0 + t * 16 + lr) * 32 + q8]);
        }
        #pragma unroll
        for (int t = 0; t < 4; t++)
            bf[t] = *reinterpret_cast<const short8*>(&Bs[(n0 + t * 16 + lr) * 32 + q8]);
        #pragma unroll
        for (int mt = 0; mt < 4; mt++)
            #pragma unroll
            for (int nt = 0; nt < 4; nt++)
                acc[mt][nt] = __builtin_amdgcn_mfma_f32_16x16x32_bf16(
                    af[mt], bf[nt], acc[mt][nt], 0, 0, 0);
    }

    const float* bp; float* op; int ostr; int c0; bool act = false;
    if (bn < 256)      { bp = b0; op = o0; ostr = 256; c0 = bn; }
    else if (bn < 768) { bp = b1; op = o1; ostr = 512; c0 = bn - 256; }
    else               { bp = b2; op = o2; ostr = 256; c0 = bn - 768; act = true; }
    const bool donorm = NORM && (bn < 512);

    float bv[4];
    #pragma unroll
    for (int nt = 0; nt < 4; nt++) bv[nt] = bp[c0 + n0 + nt * 16 + lr];

    #pragma unroll
    for (int mt = 0; mt < 4; mt++) {
        #pragma unroll
        for (int r = 0; r < 4; r++) {
            float ov[4];
            #pragma unroll
            for (int nt = 0; nt < 4; nt++) ov[nt] = acc[mt][nt][r] + bv[nt];
            if (act) {
                #pragma unroll
                for (int nt = 0; nt < 4; nt++) ov[nt] = gelu_exact(ov[nt]);
            }
            if (donorm) {
                float s01 = ov[0] * ov[0] + ov[1] * ov[1];
                float s23 = ov[2] * ov[2] + ov[3] * ov[3];
                #pragma unroll
                for (int mm = 1; mm < 16; mm <<= 1) {
                    s01 += __shfl_xor(s01, mm);
                    s23 += __shfl_xor(s23, mm);
                }
                float r01 = 1.0f / fmaxf(sqrtf(s01), 1e-12f);
                float r23 = 1.0f / fmaxf(sqrtf(s23), 1e-12f);
                ov[0] *= r01; ov[1] *= r01; ov[2] *= r23; ov[3] *= r23;
            }
            int m = bm + m0 + mt * 16 + quad * 4 + r;
            #pragma unroll
            for (int nt = 0; nt < 4; nt++)
                op[(size_t)m * ostr + c0 + n0 + nt * 16 + lr] = ov[nt];
        }
    }
}

// ---------------------------------------------------------------------------
// Merged prep: [0,1024) wcat | [1024,1152) cpb | [1152,1162) tables |
// [1162,1274) lmask
// ---------------------------------------------------------------------------
__global__ __launch_bounds__(256) void prep_misc(
    const float* __restrict__ qw, const float* __restrict__ kvw,
    const float* __restrict__ srw, unsigned short* __restrict__ wcat,
    const float* __restrict__ rct, const float* __restrict__ fc1w,
    const float* __restrict__ fc1b, const float* __restrict__ fc2w,
    const float* __restrict__ fc2b, float* __restrict__ tab,
    const float* __restrict__ temp, const float* __restrict__ sls,
    const float* __restrict__ qe,  const float* __restrict__ lt,
    const float* __restrict__ lb,
    float* __restrict__ scaleT, float* __restrict__ corrT,
    float* __restrict__ ltT, uint2* __restrict__ lmask)
{
    int bid = blockIdx.x, tid = threadIdx.x;
    if (bid < 1024) {
        int gid = bid * 256 + tid;
        int n = gid >> 8, k = gid & 255;
        float v;
        if (n < 256)      v = qw[k * 256 + n];
        else if (n < 768) v = kvw[k * 512 + (n - 256)];
        else              v = srw[k * 256 + (n - 768)];
        wcat[gid] = f2bf(v);
    } else if (bid < 1152) {
        int gid = (bid - 1024) * 256 + tid;
        if (gid >= 4096 * 8) return;
        int t = gid >> 3, h = gid & 7;
        float c0 = rct[t * 2 + 0], c1 = rct[t * 2 + 1];
        float acc = 0.f;
        for (int i = 0; i < 512; i++) {
            float hid = fmaxf(c0 * fc1w[i] + c1 * fc1w[512 + i] + fc1b[i], 0.f);
            acc += hid * fc2w[i * 8 + h];
        }
        tab[t * 8 + h] = acc + fc2b[h];
    } else if (bid < 1162) {
        int g = (bid - 1152) * 256 + tid;
        if (g < 8) {
            scaleT[g] = log1pf(expf(temp[g])) * sls[0];
        } else if (g < 80) {
            int h = (g - 8) / 9, e = (g - 8) % 9;
            float s = 0.f;
            for (int d = 0; d < 32; d++) s += qe[h * 32 + d] * lt[(h * 32 + d) * 9 + e];
            corrT[h * 9 + e] = lb[h * 9 + e] - s;
        } else if (g < 80 + 8 * 9 * 32) {
            int g2 = g - 80;
            int h = g2 / 288, rem = g2 % 288;
            int e = rem / 32, d = rem & 31;
            ltT[(h * 9 + e) * 32 + d] = lt[(h * 32 + d) * 9 + e];
        }
    } else {
        int pos = bid - 1162;               // 0..111 = (i, half)
        int i = pos >> 1, half = pos & 1;
        int j0 = half * TJ;
        int w = tid >> 6, lane = tid & 63;
        int lr = lane & 15, quad = lane >> 4;
        int kh = w >> 1, qt = w & 1;
        int jl = qt * 16 + lr;
        unsigned lpk0 = 0, lpk1 = 0;
        for (int it = 0; it < 3; it++) {
            int kbase = (2 * it + kh) * 16 + quad * 4;
            for (int r = 0; r < 4; r++) {
                int kk = kbase + r;
                int r30 = (kk >= 60) ? 2 : (kk >= 30 ? 1 : 0);
                int cm  = kk - r30 * 30;
                int d   = cm - jl;
                int gi  = i - 1 + r30, gj = j0 - 1 + cm;
                bool vld = (kk < NLOC) & ((unsigned)d <= 2u)
                         & (gi >= 0) & (gi < WID) & (gj >= 0) & (gj < WID);
                unsigned nib = vld ? (unsigned)(r30 * 3 + d) : 15u;
                if (it < 2) lpk0 |= nib << ((it * 4 + r) * 4);
                else        lpk1 |= nib << (r * 4);
            }
        }
        lmask[pos * 256 + tid] = make_uint2(lpk0, lpk1);
    }
}

// ---------------------------------------------------------------------------
// 8x8 average pool of gelu'd sr output + LayerNorm -> fp32 xp.
// Blocks >= 392: pool-bias gather.
// ---------------------------------------------------------------------------
__global__ __launch_bounds__(256) void pool_ln(
    const float* __restrict__ xs, const float* __restrict__ g,
    const float* __restrict__ bb, float* __restrict__ xp,
    const float* __restrict__ tab, const int* __restrict__ rpi,
    float* __restrict__ pb)
{
    if (blockIdx.x >= 392) {
        int gg = (blockIdx.x - 392) * 256 + threadIdx.x;
        if (gg >= NSEQ * PLEN) return;
        int idx = rpi[gg];
        const float* src = &tab[(size_t)idx * 8];
        float4 a = *reinterpret_cast<const float4*>(src);
        float4 bq = *reinterpret_cast<const float4*>(src + 4);
        *reinterpret_cast<float4*>(&pb[(size_t)gg * 8])     = a;
        *reinterpret_cast<float4*>(&pb[(size_t)gg * 8 + 4]) = bq;
        return;
    }
    int b = blockIdx.x / PLEN, p = blockIdx.x % PLEN;
    int ph = p / 7, pw_ = p % 7;
    int c = threadIdx.x;
    float s = 0.f;
    #pragma unroll
    for (int i = 0; i < 8; i++) {
        int rowpix = (ph * 8 + i) * WID + pw_ * 8;
        const float* base = &xs[((size_t)b * NSEQ + rowpix) * CDIM + c];
        #pragma unroll
        for (int jj = 0; jj < 8; jj++) s += base[(size_t)jj * CDIM];
    }
    s *= (1.f / 64.f);

    float ssum = s, ssq = s * s;
    #pragma unroll
    for (int m = 32; m > 0; m >>= 1) {
        ssum += __shfl_xor(ssum, m);
        ssq  += __shfl_xor(ssq, m);
    }
    __shared__ float r1[4], r2[4];
    int wv = threadIdx.x >> 6;
    if ((threadIdx.x & 63) == 0) { r1[wv] = ssum; r2[wv] = ssq; }
    __syncthreads();
    float tsum = r1[0] + r1[1] + r1[2] + r1[3];
    float tsq  = r2[0] + r2[1] + r2[2] + r2[3];
    float mu  = tsum * (1.f / 256.f);
    float var = tsq * (1.f / 256.f) - mu * mu;
    float o = (s - mu) * rsqrtf(var + 1e-5f) * g[c] + bb[c];
    xp[(size_t)blockIdx.x * CDIM + c] = o;
}

// ---------------------------------------------------------------------------
// fp32 kvp GEMM (M=392, N=512, K=256) + pwt transpose on the extra grid row.
// R7: k-half (bn<256) is L2-NORMALIZED per 32-col head group in the epilogue
// (same fp32 shuffle tree attn used — bit-identical values) so attn's Khi
// staging needs no per-block normalize.
// ---------------------------------------------------------------------------
__global__ __launch_bounds__(256) void kvp_pwt(
    const float* __restrict__ A, const float* __restrict__ Bw,
    const float* __restrict__ bias, float* __restrict__ C,
    const float* __restrict__ pw, unsigned short* __restrict__ pwt)
{
    if (blockIdx.y == 7) {
        int base = blockIdx.x * 256 + threadIdx.x;   // 0..2047
        for (int t = base; t < 65536; t += 2048) {
            int n = t >> 8, k = t & 255;
            pwt[t] = f2bf(pw[k * 256 + n]);
        }
        return;
    }
    const int M = BATCH * PLEN, N = 512, K = 256;
    __shared__ float Asm[16][68];
    __shared__ float Bsm[16][68];
    const int tid = threadIdx.x;
    const int tx  = tid & 15, ty = tid >> 4;
    const int bm  = blockIdx.y * 64, bn = blockIdx.x * 64;
    float acc[4][4] = {};

    const int am  = tid >> 2;
    const int ak  = (tid & 3) * 4;
    const int bk  = tid >> 4;
    const int bn4 = (tid & 15) * 4;

    for (int k0 = 0; k0 < K; k0 += 16) {
        float4 av = make_float4(0.f, 0.f, 0.f, 0.f);
        if (bm + am < M)
            av = *reinterpret_cast<const float4*>(&A[(size_t)(bm + am) * K + k0 + ak]);
        Asm[ak+0][am] = av.x; Asm[ak+1][am] = av.y; Asm[ak+2][am] = av.z; Asm[ak+3][am] = av.w;

        float4 bv = *reinterpret_cast<const float4*>(&Bw[(size_t)(k0 + bk) * N + bn + bn4]);
        Bsm[bk][bn4+0] = bv.x; Bsm[bk][bn4+1] = bv.y; Bsm[bk][bn4+2] = bv.z; Bsm[bk][bn4+3] = bv.w;
        __syncthreads();

        #pragma unroll
        for (int kk = 0; kk < 16; kk++) {
            float a0 = Asm[kk][ty*4+0], a1 = Asm[kk][ty*4+1], a2 = Asm[kk][ty*4+2], a3 = Asm[kk][ty*4+3];
            float b0 = Bsm[kk][tx*4+0], b1 = Bsm[kk][tx*4+1], b2 = Bsm[kk][tx*4+2], b3 = Bsm[kk][tx*4+3];
            acc[0][0] += a0*b0; acc[0][1] += a0*b1; acc[0][2] += a0*b2; acc[0][3] += a0*b3;
            acc[1][0] += a1*b0; acc[1][1] += a1*b1; acc[1][2] += a1*b2; acc[1][3] += a1*b3;
            acc[2][0] += a2*b0; acc[2][1] += a2*b1; acc[2][2] += a2*b2; acc[2][3] += a2*b3;
            acc[3][0] += a3*b0; acc[3][1] += a3*b1; acc[3][2] += a3*b2; acc[3][3] += a3*b3;
        }
        __syncthreads();
    }

    const int n0 = bn + tx * 4;
    float4 bsv = *reinterpret_cast<const float4*>(&bias[n0]);
    const bool knorm = (bn < 256);
    #pragma unroll
    for (int r = 0; r < 4; r++) {
        int m = bm + ty * 4 + r;
        float4 o;
        o.x = acc[r][0] + bsv.x;
        o.y = acc[r][1] + bsv.y;
        o.z = acc[r][2] + bsv.z;
        o.w = acc[r][3] + bsv.w;
        if (knorm) {
            // 32-col head-group normalize: 8-lane shuffle tree (same fp32
            // op order as attn's old Khi normalize — bit-identical).
            float ss = o.x * o.x + o.y * o.y + o.z * o.z + o.w * o.w;
            ss += __shfl_xor(ss, 1); ss += __shfl_xor(ss, 2); ss += __shfl_xor(ss, 4);
            float rn = 1.0f / fmaxf(sqrtf(ss), 1e-12f);
            o.x *= rn; o.y *= rn; o.z *= rn; o.w *= rn;
        }
        if (m < M)
            *reinterpret_cast<float4*>(&C[(size_t)m * N + n0]) = o;
    }
}

// ---------------------------------------------------------------------------
// MFMA fused attention, R14 = R13 (ltS transposed [nib][33]) with Khi
// staging simplified: kvp k-half arrives pre-normalized from kvp_pwt.
// ---------------------------------------------------------------------------
__global__ __launch_bounds__(256, 6) void attn_tile(
    const float* __restrict__ qn,   // (B,N,256)  L2-normalized q
    const float* __restrict__ kvb,  // (B,N,512)  [k normalized | v]
    const float* __restrict__ kvp,  // (B,49,512) [k_pool NORMALIZED | v_pool]
    const float* __restrict__ pb,   // (N,49,8)   pool bias gathered
    const float* __restrict__ scaleT, // (8)
    const float* __restrict__ corrT,  // (8,9)
    const float* __restrict__ ltT,    // (8,9,32)
    const float* __restrict__ qe,   // (8,32)
    const float* __restrict__ rpb,  // (8,9)
    const uint2* __restrict__ lmask,// (112,256) packed band nibbles
    unsigned short* __restrict__ ab)// (B,N,256) bf16 out
{
    __shared__ char sm[25920];
    _Float16*  KlocH = (_Float16*)(sm);            // [96][40] fp16   7680  (A)
    _Float16*  KlocL = (_Float16*)(sm + 7680);     // [96][40] fp16   7680  (A)
    _Float16*  Khi   = (_Float16*)(sm + 15360);    // [64][40] fp16   5120  (A)
    _Float16*  Qhi   = (_Float16*)(sm + 20480);    // [32][40] fp16   2560  (A)
    _Float16*  Qlo   = (_Float16*)(sm + 23040);    // [32][40] fp16   2560  (A end 25600)
    _Float16*  Aall  = (_Float16*)(sm);            // [32][KT] fp16  10752  (B)
    _Float16*  VT    = (_Float16*)(sm + 10752);    // [32][KT] fp16  10752  (B end 21504)
    float*     ltS   = (float*)(sm + 21504);       // [16][33] fp32   2112  (aliased, post-S2)
    float*     psum  = (float*)(sm + 25600);       // [4][16] fp32     256  (static)
    float*     erpbS = (float*)(sm + 25856);       // [16] fp32         64  (static)

    const int tid  = threadIdx.x;
    const int w    = tid >> 6, lane = tid & 63;
    const int lr   = lane & 15, quad = lane >> 4;
    const int q8   = quad * 8;
    const int bid  = blockIdx.x;
    const int half = bid & 1;
    const int rest = bid >> 1;
    const int i    = rest % WID;
    const int h    = (rest / WID) & 7;
    const int b    = rest / (WID * NHEADS);
    const int j0   = half * TJ;

    const int kh = w >> 1;          // key half (tiles 2*it+kh)
    const int qt = w & 1;           // query tile
    const int jl = qt * 16 + lr;    // this lane's query row (0..31)

    const float scale = scaleT[h];
    const float inv = 1.0f / scale;

    // ---- band-mask nibbles (precomputed, (b,h)-invariant) ----
    const uint2 lm = lmask[(i * 2 + half) * 256 + tid];

    // ---- erpbS: exp(rpb) table, slots 9..15 = 0 ----
    if (tid < 16) erpbS[tid] = (tid < 9) ? __expf(rpb[h * 9 + tid]) : 0.f;

    // ---- T14: issue first-iteration V loads NOW (consumed post-S2) ----
    float4 va0, vb0; bool v0a, v1a;
    {
        int p = tid >> 3, d4 = tid & 7;
        int kk0 = 2 * p;
        int r = kk0 / 30, c0 = kk0 % 30;
        int gi = i - 1 + r;
        int gj0 = j0 - 1 + c0, gj1 = gj0 + 1;
        v0a = (gi >= 0) & (gi < WID) & (gj0 >= 0) & (gj0 < WID);
        v1a = (gi >= 0) & (gi < WID) & (gj1 >= 0) & (gj1 < WID);
        int gic  = min(max(gi, 0), WID - 1);
        int gj0c = min(max(gj0, 0), WID - 1), gj1c = min(max(gj1, 0), WID - 1);
        va0 = *reinterpret_cast<const float4*>(
            &kvb[((size_t)(b * NSEQ + gic * WID + gj0c)) * 512 + 256 + h * HDIM + d4 * 4]);
        vb0 = *reinterpret_cast<const float4*>(
            &kvb[((size_t)(b * NSEQ + gic * WID + gj1c)) * 512 + 256 + h * HDIM + d4 * 4]);
    }
    float4 vp0;
    {
        int m = tid >> 3, d4 = tid & 7;
        vp0 = *reinterpret_cast<const float4*>(
            &kvp[((size_t)(b * PLEN + m)) * 512 + 256 + h * HDIM + d4 * 4]);
    }

    // ---- prefetch pool biases for this lane's pool regs (tiles it=3,4) ----
    float pbr[2][4];
    #pragma unroll
    for (int it = 0; it < 2; it++) {
        int kt = 6 + 2 * it + kh;
        int pbase = (kt - 6) * 16 + quad * 4;
        #pragma unroll
        for (int r = 0; r < 4; r++) {
            int p = pbase + r;
            float bv = 0.f;
            if (p < PLEN && jl < TJ) {
                int n = i * WID + j0 + jl;
                bv = pb[((size_t)n * PLEN + p) * 8 + h];
            }
            pbr[it][r] = bv;
        }
    }

    // ---- stage scaled q (hi/lo fp16), zero-pad rows 28..31 ----
    if (tid < 224) {
        int ql_ = tid >> 3, d4 = tid & 7;
        int n  = i * WID + j0 + ql_;
        float4 qv = *reinterpret_cast<const float4*>(&qn[((size_t)(b * NSEQ + n)) * CDIM + h * HDIM + d4 * 4]);
        float4 ev = *reinterpret_cast<const float4*>(&qe[h * HDIM + d4 * 4]);
        float sx = (qv.x + ev.x) * scale, sy = (qv.y + ev.y) * scale;
        float sz = (qv.z + ev.z) * scale, sw = (qv.w + ev.w) * scale;
        half4_t hv = { (_Float16)sx, (_Float16)sy, (_Float16)sz, (_Float16)sw };
        half4_t lv = { (_Float16)(sx - (float)hv.x), (_Float16)(sy - (float)hv.y),
                       (_Float16)(sz - (float)hv.z), (_Float16)(sw - (float)hv.w) };
        *reinterpret_cast<half4_t*>(&Qhi[ql_ * 40 + d4 * 4]) = hv;
        *reinterpret_cast<half4_t*>(&Qlo[ql_ * 40 + d4 * 4]) = lv;
    } else {
        int t = tid - 224;
        int ql_ = 28 + (t >> 3), d4 = t & 7;
        half4_t z = {};
        *reinterpret_cast<half4_t*>(&Qhi[ql_ * 40 + d4 * 4]) = z;
        *reinterpret_cast<half4_t*>(&Qlo[ql_ * 40 + d4 * 4]) = z;
    }

    // ---- stage Khi [64 rows]: pre-normalized pool k 0..48 | ltT 49..57 | zero
    for (int idx = tid; idx < 64 * 8; idx += 256) {
        int c = idx >> 3, d4 = idx & 7;
        half4_t hv;
        if (c < PLEN) {
            float4 k4 = *reinterpret_cast<const float4*>(&kvp[((size_t)(b * PLEN + c)) * 512 + h * HDIM + d4 * 4]);
            hv.x = (_Float16)k4.x; hv.y = (_Float16)k4.y;
            hv.z = (_Float16)k4.z; hv.w = (_Float16)k4.w;
        } else if (c < 58) {
            int t = c - PLEN;
            float4 l4 = *reinterpret_cast<const float4*>(&ltT[((size_t)h * 9 + t) * 32 + d4 * 4]);
            hv.x = (_Float16)l4.x; hv.y = (_Float16)l4.y;
            hv.z = (_Float16)l4.z; hv.w = (_Float16)l4.w;
        } else {
            hv = half4_t{};
        }
        *reinterpret_cast<half4_t*>(&Khi[c * 40 + d4 * 4]) = hv;
    }

    // ---- stage local k as fp16 hi/lo ----
    for (int idx = tid; idx < NLOC * 8; idx += 256) {
        int kk = idx >> 3, d4 = idx & 7;
        int r = kk / 30, c = kk % 30;
        int gi = i - 1 + r, gj = j0 - 1 + c;
        int gic = min(max(gi, 0), WID - 1), gjc = min(max(gj, 0), WID - 1);
        float4 k4 = *reinterpret_cast<const float4*>(
            &kvb[((size_t)(b * NSEQ + gic * WID + gjc)) * 512 + h * HDIM + d4 * 4]);
        half4_t hv = { (_Float16)k4.x, (_Float16)k4.y, (_Float16)k4.z, (_Float16)k4.w };
        half4_t lv = { (_Float16)(k4.x - (float)hv.x), (_Float16)(k4.y - (float)hv.y),
                       (_Float16)(k4.z - (float)hv.z), (_Float16)(k4.w - (float)hv.w) };
        *reinterpret_cast<half4_t*>(&KlocH[kk * 40 + d4 * 4]) = hv;
        *reinterpret_cast<half4_t*>(&KlocL[kk * 40 + d4 * 4]) = lv;
    }
    // zero pad rows 90..95
    if (tid < 48) {
        int kk = 90 + (tid >> 3), d4 = tid & 7;
        half4_t z = {};
        *reinterpret_cast<half4_t*>(&KlocH[kk * 40 + d4 * 4]) = z;
        *reinterpret_cast<half4_t*>(&KlocL[kk * 40 + d4 * 4]) = z;
    }
    __syncthreads();   // S1

    // ================= transposed score MFMAs: C[key][query] =================
    half8 qh = *reinterpret_cast<const half8*>(&Qhi[jl * 40 + q8]);
    half8 qlo = *reinterpret_cast<const half8*>(&Qlo[jl * 40 + q8]);
    f32x4 c5[5];
    __builtin_amdgcn_s_setprio(1);
    #pragma unroll
    for (int it = 0; it < 3; it++) {        // local tiles (kt = 2*it+kh < 6)
        int kt = 2 * it + kh;
        half8 ah = *reinterpret_cast<const half8*>(&KlocH[(kt * 16 + lr) * 40 + q8]);
        half8 al = *reinterpret_cast<const half8*>(&KlocL[(kt * 16 + lr) * 40 + q8]);
        f32x4 c = {};
        c = __builtin_amdgcn_mfma_f32_16x16x32_f16(ah, qh, c, 0, 0, 0);
        c = __builtin_amdgcn_mfma_f32_16x16x32_f16(ah, qlo, c, 0, 0, 0);
        c = __builtin_amdgcn_mfma_f32_16x16x32_f16(al, qh, c, 0, 0, 0);
        c5[it] = c;
    }
    #pragma unroll
    for (int it = 3; it < 5; it++) {        // pool tiles (kt >= 6)
        int kt = 2 * it + kh;
        half8 kf = *reinterpret_cast<const half8*>(&Khi[((kt - 6) * 16 + lr) * 40 + q8]);
        f32x4 c = {};
        c = __builtin_amdgcn_mfma_f32_16x16x32_f16(kf, qh, c, 0, 0, 0);
        c = __builtin_amdgcn_mfma_f32_16x16x32_f16(kf, qlo, c, 0, 0, 0);
        c5[it] = c;
    }
    __builtin_amdgcn_s_setprio(0);

    // ===== in-register exp (mask via erpbS multiply) + partial sum =====
    float pe[5][4];
    float pp = 0.f;
    #pragma unroll
    for (int it = 0; it < 3; it++) {        // local
        #pragma unroll
        for (int r = 0; r < 4; r++) {
            unsigned nib = (it < 2) ? ((lm.x >> ((it * 4 + r) * 4)) & 15u)
                                    : ((lm.y >> (r * 4)) & 15u);
            float v = __expf(c5[it][r]) * erpbS[nib];
            pe[it][r] = v; pp += v;
        }
    }
    #pragma unroll
    for (int it = 3; it < 5; it++) {        // pool
        int kt = 2 * it + kh;
        int pbase = (kt - 6) * 16 + quad * 4;
        #pragma unroll
        for (int r = 0; r < 4; r++) {
            int p = pbase + r;
            float v = 0.f;
            if (p < PLEN) v = __expf(c5[it][r] + pbr[it - 3][r]);
            pe[it][r] = v; pp += v;
        }
    }
    pp += __shfl_xor(pp, 16);
    pp += __shfl_xor(pp, 32);
    if (lane < 16) psum[w * 16 + lr] = pp;
    __syncthreads();   // S2 — phase-A LDS dead; psum visible

    // ===== post-S2: lt extras to ltS[nib][jl] stride 33 (kh==1, tile 9) =====
    if (kh == 1) {
        #pragma unroll
        for (int r = 0; r < 4; r++) {
            int p = 48 + quad * 4 + r;      // tile 9: key 144+quad*4+r
            int e = p - 49;                 // -1..14
            bool real = (e >= 0) & (e < 9);
            float val = real ? (c5[4][r] * inv + corrT[h * 9 + e]) : 0.f;
            int slot = real ? e : ((e < 0) ? 15 : e);
            ltS[slot * 33 + jl] = val;
        }
    }

    // ===== V_T writes: prefetched iter0 + inline tails =====
    {
        int p = tid >> 3, d4 = tid & 7;
        int kk0 = 2 * p;
        if (!v0a) va0 = make_float4(0.f, 0.f, 0.f, 0.f);
        if (!v1a) vb0 = make_float4(0.f, 0.f, 0.f, 0.f);
        half2_t p0 = { (_Float16)va0.x, (_Float16)vb0.x };
        half2_t p1 = { (_Float16)va0.y, (_Float16)vb0.y };
        half2_t p2 = { (_Float16)va0.z, (_Float16)vb0.z };
        half2_t p3 = { (_Float16)va0.w, (_Float16)vb0.w };
        *reinterpret_cast<half2_t*>(&VT[(d4 * 4 + 0) * KT + kk0]) = p0;
        *reinterpret_cast<half2_t*>(&VT[(d4 * 4 + 1) * KT + kk0]) = p1;
        *reinterpret_cast<half2_t*>(&VT[(d4 * 4 + 2) * KT + kk0]) = p2;
        *reinterpret_cast<half2_t*>(&VT[(d4 * 4 + 3) * KT + kk0]) = p3;
    }
    if (tid < 104) {                         // local tail: idx = tid + 256
        int idx = tid + 256;
        int p = idx >> 3, d4 = idx & 7;
        int kk0 = 2 * p;
        int r = kk0 / 30, c0 = kk0 % 30;
        int gi = i - 1 + r;
        int gj0 = j0 - 1 + c0, gj1 = gj0 + 1;
        bool v0 = (gi >= 0) & (gi < WID) & (gj0 >= 0) & (gj0 < WID);
        bool v1 = (gi >= 0) & (gi < WID) & (gj1 >= 0) & (gj1 < WID);
        int gic  = min(max(gi, 0), WID - 1);
        int gj0c = min(max(gj0, 0), WID - 1), gj1c = min(max(gj1, 0), WID - 1);
        float4 va = *reinterpret_cast<const float4*>(
            &kvb[((size_t)(b * NSEQ + gic * WID + gj0c)) * 512 + 256 + h * HDIM + d4 * 4]);
        float4 vb = *reinterpret_cast<const float4*>(
            &kvb[((size_t)(b * NSEQ + gic * WID + gj1c)) * 512 + 256 + h * HDIM + d4 * 4]);
        if (!v0) va = make_float4(0.f, 0.f, 0.f, 0.f);
        if (!v1) vb = make_float4(0.f, 0.f, 0.f, 0.f);
        half2_t p0 = { (_Float16)va.x, (_Float16)vb.x };
        half2_t p1 = { (_Float16)va.y, (_Float16)vb.y };
        half2_t p2 = { (_Float16)va.z, (_Float16)vb.z };
        half2_t p3 = { (_Float16)va.w, (_Float16)vb.w };
        *reinterpret_cast<half2_t*>(&VT[(d4 * 4 + 0) * KT + kk0]) = p0;
        *reinterpret_cast<half2_t*>(&VT[(d4 * 4 + 1) * KT + kk0]) = p1;
        *reinterpret_cast<half2_t*>(&VT[(d4 * 4 + 2) * KT + kk0]) = p2;
        *reinterpret_cast<half2_t*>(&VT[(d4 * 4 + 3) * KT + kk0]) = p3;
    }
    {                                        // pool iter0 (prefetched)
        int m = tid >> 3, d4 = tid & 7;
        VT[(d4 * 4 + 0) * KT + 96 + m] = (_Float16)vp0.x;
        VT[(d4 * 4 + 1) * KT + 96 + m] = (_Float16)vp0.y;
        VT[(d4 * 4 + 2) * KT + 96 + m] = (_Float16)vp0.z;
        VT[(d4 * 4 + 3) * KT + 96 + m] = (_Float16)vp0.w;
    }
    if (tid < 136) {                         // pool tail: idx = tid + 256
        int idx = tid + 256;
        int m = idx >> 3, d4 = idx & 7;
        float4 v4 = *reinterpret_cast<const float4*>(
            &kvp[((size_t)(b * PLEN + m)) * 512 + 256 + h * HDIM + d4 * 4]);
        VT[(d4 * 4 + 0) * KT + 96 + m] = (_Float16)v4.x;
        VT[(d4 * 4 + 1) * KT + 96 + m] = (_Float16)v4.y;
        VT[(d4 * 4 + 2) * KT + 96 + m] = (_Float16)v4.z;
        VT[(d4 * 4 + 3) * KT + 96 + m] = (_Float16)v4.w;
    }
    // zero VT pad cols (90..95, 145..159)
    for (int idx = tid; idx < 32 * 6; idx += 256) {
        int d = idx / 6, c = idx % 6;
        VT[d * KT + 90 + c] = (_Float16)0.f;
    }
    for (int idx = tid; idx < 32 * 15; idx += 256) {
        int d = idx / 15, c = idx % 15;
        VT[d * KT + 145 + c] = (_Float16)0.f;
    }
    __syncthreads();   // S2b — ltS visible; VT done

    // ===== normalize + lt-extra (transposed ltS read) + scatter =====
    {
        float tot = psum[qt * 16 + lr] + psum[qt * 16 + 32 + lr];
        float rtot = 1.0f / tot;
        #pragma unroll
        for (int it = 0; it < 3; it++) {    // local tiles
            int kt = 2 * it + kh;
            int kbase = kt * 16 + quad * 4;
            float a[4];
            #pragma unroll
            for (int r = 0; r < 4; r++) {
                unsigned nib = (it < 2) ? ((lm.x >> ((it * 4 + r) * 4)) & 15u)
                                        : ((lm.y >> (r * 4)) & 15u);
                a[r] = pe[it][r] * rtot + ltS[nib * 33 + jl];
            }
            half2_t h01 = { (_Float16)a[0], (_Float16)a[1] };
            half2_t h23 = { (_Float16)a[2], (_Float16)a[3] };
            *reinterpret_cast<half2_t*>(&Aall[jl * KT + kbase])     = h01;
            *reinterpret_cast<half2_t*>(&Aall[jl * KT + kbase + 2]) = h23;
        }
        #pragma unroll
        for (int it = 3; it < 5; it++) {    // pool tiles
            int kt = 2 * it + kh;
            int kbase = kt * 16 + quad * 4;
            half2_t h01 = { (_Float16)(pe[it][0] * rtot), (_Float16)(pe[it][1] * rtot) };
            half2_t h23 = { (_Float16)(pe[it][2] * rtot), (_Float16)(pe[it][3] * rtot) };
            *reinterpret_cast<half2_t*>(&Aall[jl * KT + kbase])     = h01;
            *reinterpret_cast<half2_t*>(&Aall[jl * KT + kbase + 2]) = h23;
        }
    }
    __syncthreads();   // S3

    // ================= unified AV via MFMA, direct bf16 store ===============
    {
        int mt = w >> 1, nt = w & 1;
        f32x4 c = {};
        __builtin_amdgcn_s_setprio(1);
        #pragma unroll
        for (int kk = 0; kk < 5; kk++) {
            half8 af = *reinterpret_cast<const half8*>(&Aall[(mt * 16 + lr) * KT + kk * 32 + q8]);
            half8 bv = *reinterpret_cast<const half8*>(&VT[(nt * 16 + lr) * KT + kk * 32 + q8]);
            c = __builtin_amdgcn_mfma_f32_16x16x32_f16(af, bv, c, 0, 0, 0);
        }
        __builtin_amdgcn_s_setprio(0);
        int dim = nt * 16 + lr;
        #pragma unroll
        for (int r = 0; r < 4; r++) {
            int pr = mt * 16 + quad * 4 + r;
            if (pr < TJ) {
                int n = i * WID + j0 + pr;
                ab[((size_t)(b * NSEQ + n)) * CDIM + h * HDIM + dim] = f2bf(c[r]);
            }
        }
    }
}

// ---------------------------------------------------------------------------
// Workspace (floats), total 26,023,936 = 104.1 MB (unchanged):
//   qn @0 | kvbuf @6422528 | xs @19267584 | xp @25690112 (fp32)
//   kvp @25790464 | tab @25991168
// xs region: ab bf16 [0:3211264) halfs; pwt bf16 at float offset 3211264.
// d_out scratch until proj:
//   wcat halfs at float 3211264 | scaleT @3420000 | corrT @3420016 |
//   ltT @3420100 | pb @3500000 | lmask @4800000
// ---------------------------------------------------------------------------
extern "C" void kernel_launch(void* const* d_in, const int* in_sizes, int n_in,
                              void* d_out, int out_size, void* d_ws, size_t ws_size,
                              hipStream_t stream)
{
    const float* x    = (const float*)d_in[0];
    const float* sls  = (const float*)d_in[1];
    const float* rct  = (const float*)d_in[2];
    const float* q_w  = (const float*)d_in[3];
    const float* q_b  = (const float*)d_in[4];
    const float* qe   = (const float*)d_in[5];
    const float* temp = (const float*)d_in[6];
    const float* kv_w = (const float*)d_in[7];
    const float* kv_b = (const float*)d_in[8];
    const float* sr_w = (const float*)d_in[9];
    const float* sr_b = (const float*)d_in[10];
    const float* ng   = (const float*)d_in[11];
    const float* nb   = (const float*)d_in[12];
    const float* f1w  = (const float*)d_in[13];
    const float* f1b  = (const float*)d_in[14];
    const float* f2w  = (const float*)d_in[15];
    const float* f2b  = (const float*)d_in[16];
    const float* rpb  = (const float*)d_in[17];
    const float* lt   = (const float*)d_in[18];
    const float* lb   = (const float*)d_in[19];
    const float* pw   = (const float*)d_in[20];
    const float* pbi  = (const float*)d_in[21];
    const int*   rpi  = (const int*)d_in[22];

    if (ws_size < (size_t)26023936 * sizeof(float)) return;

    float* ws  = (float*)d_ws;
    float* qn  = ws;
    float* kvbuf = ws + 6422528;
    float* xs  = ws + 19267584;
    float* xp  = ws + 25690112;
    float* kvp = ws + 25790464;
    float* tab = ws + 25991168;
    float* out = (float*)d_out;

    unsigned short* ab   = (unsigned short*)xs;                  // bf16 attn out
    unsigned short* pwt  = (unsigned short*)(xs + 3211264);      // bf16 proj w^T
    unsigned short* wcat = (unsigned short*)(out + 3211264);     // bf16 [q|kv|sr]^T
    float* scaleT = out + 3420000;
    float* corrT  = out + 3420016;
    float* ltT    = out + 3420100;
    float* pbt    = out + 3500000;
    uint2* lmaskT = (uint2*)(out + 4800000);

    dim3 blk(256);

    // prep: wcat, cpb table, scale/corr/ltT tables, lmask (one launch)
    prep_misc<<<1274, blk, 0, stream>>>(q_w, kv_w, sr_w, wcat,
                                        rct, f1w, f1b, f2w, f2b, tab,
                                        temp, sls, qe, lt, lb,
                                        scaleT, corrT, ltT, lmaskT);

    // fused q|kv|sr MFMA GEMM, fp32-A staging, fused L2-norm epilogue
    gemm_bt<1, 1><<<dim3(8, 196), blk, 0, stream>>>(x, wcat, q_b, kv_b, sr_b,
                                                    qn, kvbuf, xs);

    // 8x8 pool + LayerNorm -> fp32 xp; blocks >= 392 do the pb gather
    pool_ln<<<993, blk, 0, stream>>>(xs, ng, nb, xp, tab, rpi, pbt);

    // pooled kv projection (fp32, k-half L2-normalized) + pwt transpose
    kvp_pwt<<<dim3(8, 8), blk, 0, stream>>>(xp, kv_w, kv_b, kvp, pw, pwt);

    // fused attention -> bf16 ab
    attn_tile<<<BATCH * NHEADS * WID * 2, blk, 0, stream>>>(
        qn, kvbuf, kvp, pbt, scaleT, corrT, ltT, qe, rpb, lmaskT, ab);

    // output projection (MFMA, no norm, bf16 A)
    gemm_bt<0, 0><<<dim3(2, 196), blk, 0, stream>>>(ab, pwt, pbi, pbi, pbi,
                                                    out, out, out);
}